// Round 3
// baseline (386.453 us; speedup 1.0000x reference)
//
#include <hip/hip_runtime.h>
#include <math.h>

// Problem constants
#define B_   32
#define N_   100
#define ND_  128   // NODE_DIM
#define ED_  64    // EDGE_DIM
#define HID_ 128
#define EPS_ 1e-5f
#define NNODE (B_*N_)                 // 3200
#define EDGE_SAMPLES ((float)(B_*N_*N_))  // 320000

// Workspace layout (in floats)
#define WS_A      0          // A  = h @ WA^T   [3200][128]
#define WS_BV     409600     // Bv = h @ WB^T   [3200][128]
#define WS_HIN    819200     // h_in = h @ WU^T [3200][128]
#define WS_HNB    1228800    // h_nb = h @ WV^T [3200][128]
#define WS_M      1638400    // m aggregation   [3200][128]
#define WS_STATS  2048000    // edge BN stats [32 slots][2][128] = 8192 floats
#define WS_NSTATS (WS_STATS + 8192)  // node BN stats [2][128] = 256 floats
// total: 2,056,704 floats ~= 8.2 MB

// ---------------------------------------------------------------------------
// K1: node projections. grid (100, 4), block 256. 32 nodes per block.
//   blockIdx.y: 0 -> WA -> A, 1 -> WB -> Bv, 2 -> WU -> h_in, 3 -> WV -> h_nb
// ---------------------------------------------------------------------------
__global__ __launch_bounds__(256) void k1_proj(
    const float* __restrict__ h,
    const float* __restrict__ WA, const float* __restrict__ WB,
    const float* __restrict__ WU, const float* __restrict__ WV,
    float* __restrict__ ws) {
  __shared__ float hT[32 * 128];      // 16 KB
  __shared__ float Wl[128 * 129];     // 66 KB, pad 129 -> bank-conflict-free
  const int t  = threadIdx.x;
  const int r0 = blockIdx.x * 32;     // first node (flat b*100+m) of this block

  const float* W;
  float* outp;
  switch (blockIdx.y) {
    case 0:  W = WA; outp = ws + WS_A;   break;
    case 1:  W = WB; outp = ws + WS_BV;  break;
    case 2:  W = WU; outp = ws + WS_HIN; break;
    default: W = WV; outp = ws + WS_HNB; break;
  }

#pragma unroll
  for (int k = 0; k < 16; ++k) {      // 32*128 = 4096 floats, coalesced
    int idx = t + k * 256;
    hT[idx] = h[r0 * 128 + idx];
  }
#pragma unroll
  for (int k = 0; k < 64; ++k) {      // 128*128 = 16384 floats, coalesced
    int idx = t + k * 256;
    int d = idx >> 7, c = idx & 127;
    Wl[d * 129 + c] = W[idx];
  }
  __syncthreads();

  const int d  = t & 127;
  const int ih = t >> 7;              // 0 or 1 -> which 16-node half
  for (int i = ih * 16; i < ih * 16 + 16; ++i) {
    float acc = 0.f;
#pragma unroll
    for (int c = 0; c < 128; ++c)
      acc += hT[i * 128 + c] * Wl[d * 129 + c];   // hT: broadcast, Wl: conflict-free
    outp[(r0 + i) * 128 + d] = acc;               // coalesced store
  }
}

// ---------------------------------------------------------------------------
// K2: edge BN statistics pass. grid 3200 (one per (b,m)), block 256.
// Recomputes eh_pre = e@WC^T + A[b,m,:] + Bv[b,n,:], accumulates per-channel
// sum & sumsq into per-b atomic slots.
// ---------------------------------------------------------------------------
__global__ __launch_bounds__(256) void k2_stats(
    const float* __restrict__ e, const float* __restrict__ WC,
    float* __restrict__ ws) {
  __shared__ float e_lds[N_ * ED_];   // 25.6 KB
  __shared__ float wcst[128 * 65];    // 33.3 KB staged WC (padded)
  __shared__ float red[256];
  const int t  = threadIdx.x;
  const int bm = blockIdx.x;
  const int b  = bm / N_;

  const float* ep = e + (size_t)bm * (N_ * ED_);
#pragma unroll
  for (int k = 0; k < 25; ++k)        // 6400 floats, coalesced
    e_lds[t + k * 256] = ep[t + k * 256];
#pragma unroll
  for (int k = 0; k < 32; ++k) {      // 8192 floats, coalesced
    int idx = t + k * 256;
    wcst[(idx >> 6) * 65 + (idx & 63)] = WC[idx];
  }
  __syncthreads();

  const int d  = t & 127;
  const int nh = t >> 7;              // neighbor half: n in [nh*50, nh*50+50)
  float wc[64];
#pragma unroll
  for (int q = 0; q < 64; ++q) wc[q] = wcst[d * 65 + q];  // conflict-free

  const float A_d = ws[WS_A + bm * 128 + d];
  const float* Bvp = ws + WS_BV + b * (N_ * 128) + d;

  float s = 0.f, sssum = 0.f;
  for (int n = nh * 50; n < nh * 50 + 50; ++n) {
    float acc = A_d + Bvp[n * 128];
    const float* er = &e_lds[n * 64];
#pragma unroll
    for (int q = 0; q < 16; ++q) {
      float4 ev = *(const float4*)(er + q * 4);   // wave-broadcast LDS read
      acc += ev.x * wc[q*4] + ev.y * wc[q*4+1] + ev.z * wc[q*4+2] + ev.w * wc[q*4+3];
    }
    s += acc;
    sssum += acc * acc;
  }

  red[t] = s;
  __syncthreads();
  if (t < 128) atomicAdd(&ws[WS_STATS + b * 256 + t], red[t] + red[t + 128]);
  __syncthreads();
  red[t] = sssum;
  __syncthreads();
  if (t < 128) atomicAdd(&ws[WS_STATS + b * 256 + 128 + t], red[t] + red[t + 128]);
}

// ---------------------------------------------------------------------------
// K4: main fused pass. grid 3200 (one per (b,m)), block 256.
// Recompute eh_pre -> BN -> relu -> *adj -> sigmoid -> exp (softmax numerator)
// -> softmax denom over n -> write e_norm + aggregate m = sum_n e_norm*h_nb.
// ---------------------------------------------------------------------------
__global__ __launch_bounds__(256) void k4_main(
    const float* __restrict__ e, const float* __restrict__ adj,
    const float* __restrict__ WC,
    const float* __restrict__ gamma_e, const float* __restrict__ beta_e,
    float* __restrict__ ws, float* __restrict__ out_enorm) {
  __shared__ float e_lds[N_ * ED_];   // 25.6 KB
  __shared__ float w_lds[N_ * 128];   // 51.2 KB; first reused to stage WC (8320 floats)
  __shared__ float adj_lds[N_];
  __shared__ float sc_lds[128], sh_lds[128];
  __shared__ float red[256];
  const int t  = threadIdx.x;
  const int bm = blockIdx.x;
  const int b  = bm / N_;

  const float* ep = e + (size_t)bm * (N_ * ED_);
#pragma unroll
  for (int k = 0; k < 25; ++k)
    e_lds[t + k * 256] = ep[t + k * 256];
#pragma unroll
  for (int k = 0; k < 32; ++k) {      // stage WC into w_lds, padded 65
    int idx = t + k * 256;
    w_lds[(idx >> 6) * 65 + (idx & 63)] = WC[idx];
  }
  if (t < N_) adj_lds[t] = adj[bm * N_ + t];
  if (t < 128) {
    // finalize edge BN: reduce 32 slots, derive scale/shift
    float S = 0.f, SS = 0.f;
#pragma unroll
    for (int j = 0; j < 32; ++j) {
      S  += ws[WS_STATS + j * 256 + t];
      SS += ws[WS_STATS + j * 256 + 128 + t];
    }
    float mean = S * (1.0f / EDGE_SAMPLES);
    float var  = SS * (1.0f / EDGE_SAMPLES) - mean * mean;
    float sc   = gamma_e[t] * rsqrtf(var + EPS_);
    sc_lds[t] = sc;
    sh_lds[t] = beta_e[t] - mean * sc;
  }
  __syncthreads();

  const int d  = t & 127;
  const int nh = t >> 7;
  float wc[64];
#pragma unroll
  for (int q = 0; q < 64; ++q) wc[q] = w_lds[d * 65 + q];
  const float A_d = ws[WS_A + bm * 128 + d];
  const float sc = sc_lds[d], sh = sh_lds[d];
  const float* Bvp = ws + WS_BV + b * (N_ * 128) + d;
  __syncthreads();   // everyone done reading staged WC before w_lds is reused

  float den = 0.f;
  for (int n = nh * 50; n < nh * 50 + 50; ++n) {
    float acc = A_d + Bvp[n * 128];
    const float* er = &e_lds[n * 64];
#pragma unroll
    for (int q = 0; q < 16; ++q) {
      float4 ev = *(const float4*)(er + q * 4);
      acc += ev.x * wc[q*4] + ev.y * wc[q*4+1] + ev.z * wc[q*4+2] + ev.w * wc[q*4+3];
    }
    float x   = fmaxf(acc * sc + sh, 0.f) * adj_lds[n];   // relu(bn) * adj
    float sig = 1.f / (1.f + __expf(-x));                 // e_weight
    float p   = __expf(sig);                              // softmax numerator
    w_lds[n * 128 + d] = p;
    den += p;
  }

  red[t] = den;
  __syncthreads();
  const float dtot = red[d] + red[d + 128];
  const float rcp  = 1.f / dtot;

  const float* hnbp = ws + WS_HNB + b * (N_ * 128) + d;
  float* outp = out_enorm + (size_t)bm * (N_ * 128) + d;
  float msg = 0.f;
  for (int n = nh * 50; n < nh * 50 + 50; ++n) {
    float v = w_lds[n * 128 + d] * rcp;   // e_norm
    outp[n * 128] = v;                    // coalesced
    msg += v * hnbp[n * 128];
  }
  __syncthreads();   // red about to be reused
  red[t] = msg;
  __syncthreads();
  if (t < 128) ws[WS_M + bm * 128 + t] = red[t] + red[t + 128];
}

// ---------------------------------------------------------------------------
// K5a: node BN statistics over m [3200][128]. grid 32, block 256.
// ---------------------------------------------------------------------------
__global__ __launch_bounds__(256) void k5a_nstats(float* __restrict__ ws) {
  __shared__ float red[256];
  const int t = threadIdx.x;
  const int j = blockIdx.x;          // 0..31, rows [j*100, (j+1)*100)
  const int d = t & 127, rh = t >> 7;
  float s = 0.f, sssum = 0.f;
  for (int r = j * 100 + rh; r < (j + 1) * 100; r += 2) {
    float v = ws[WS_M + r * 128 + d];
    s += v;
    sssum += v * v;
  }
  red[t] = s;
  __syncthreads();
  if (t < 128) atomicAdd(&ws[WS_NSTATS + t], red[t] + red[t + 128]);
  __syncthreads();
  red[t] = sssum;
  __syncthreads();
  if (t < 128) atomicAdd(&ws[WS_NSTATS + 128 + t], red[t] + red[t + 128]);
}

// ---------------------------------------------------------------------------
// K5b: h_out = h_in + relu(bn_node(m)). grid 1600, block 256 (409600 elems).
// ---------------------------------------------------------------------------
__global__ __launch_bounds__(256) void k5b_hout(
    const float* __restrict__ gamma_n, const float* __restrict__ beta_n,
    const float* __restrict__ ws, float* __restrict__ hout) {
  const int idx = blockIdx.x * 256 + threadIdx.x;   // < 409600
  const int d = idx & 127;
  float S  = ws[WS_NSTATS + d];
  float SS = ws[WS_NSTATS + 128 + d];
  float mean = S * (1.0f / (float)NNODE);
  float var  = SS * (1.0f / (float)NNODE) - mean * mean;
  float sc   = gamma_n[d] * rsqrtf(var + EPS_);
  float sh   = beta_n[d] - mean * sc;
  float mv   = ws[WS_M + idx];
  hout[idx]  = ws[WS_HIN + idx] + fmaxf(mv * sc + sh, 0.f);
}

// ---------------------------------------------------------------------------
extern "C" void kernel_launch(void* const* d_in, const int* in_sizes, int n_in,
                              void* d_out, int out_size, void* d_ws, size_t ws_size,
                              hipStream_t stream) {
  (void)in_sizes; (void)n_in; (void)out_size; (void)ws_size;
  const float* h   = (const float*)d_in[0];
  const float* e   = (const float*)d_in[1];
  const float* adj = (const float*)d_in[2];
  const float* WU  = (const float*)d_in[3];
  const float* WV  = (const float*)d_in[4];
  const float* WA  = (const float*)d_in[5];
  const float* WB  = (const float*)d_in[6];
  const float* WC  = (const float*)d_in[7];
  const float* geg = (const float*)d_in[8];   // bn_edge_gamma
  const float* geb = (const float*)d_in[9];   // bn_edge_beta
  const float* gng = (const float*)d_in[10];  // bn_node_gamma
  const float* gnb = (const float*)d_in[11];  // bn_node_beta

  float* out = (float*)d_out;                 // h_out [409600] then e_norm [40960000]
  float* ws  = (float*)d_ws;

  // zero the atomic accumulators (ws is poisoned, not re-zeroed between replays)
  hipMemsetAsync(ws + WS_STATS, 0, (8192 + 256) * sizeof(float), stream);

  k1_proj  <<<dim3(100, 4), 256, 0, stream>>>(h, WA, WB, WU, WV, ws);
  k2_stats <<<3200,         256, 0, stream>>>(e, WC, ws);
  k4_main  <<<3200,         256, 0, stream>>>(e, adj, WC, geg, geb, ws, out + 409600);
  k5a_nstats<<<32,          256, 0, stream>>>(ws);
  k5b_hout <<<1600,         256, 0, stream>>>(gng, gnb, ws, out);
}

// Round 4
// 154.562 us; speedup vs baseline: 2.5003x; 2.5003x over previous
//
#include <hip/hip_runtime.h>
#include <math.h>

// Problem constants
#define B_   32
#define N_   100
#define ND_  128   // NODE_DIM
#define ED_  64    // EDGE_DIM
#define HID_ 128
#define EPS_ 1e-5f
#define NNODE (B_*N_)                 // 3200
#define EDGE_SAMPLES ((float)(B_*N_*N_))  // 320000

// Workspace layout (in floats)
#define WS_A      0          // A  = h @ WA^T   [3200][128]
#define WS_BV     409600     // Bv = h @ WB^T   [3200][128]
#define WS_HIN    819200     // h_in = h @ WU^T [3200][128]
#define WS_HNB    1228800    // h_nb = h @ WV^T [3200][128]
#define WS_M      1638400    // m aggregation   [3200][128]
#define WS_STATS  2048000    // edge BN stats [32 slots][2][128] = 8192 floats
#define WS_NSTATS (WS_STATS + 8192)  // node BN stats [2][128] = 256 floats

typedef __attribute__((ext_vector_type(8))) short bf16x8;
typedef __attribute__((ext_vector_type(4))) float f32x4;
#define MFMA16(a,b,c) __builtin_amdgcn_mfma_f32_16x16x32_bf16(a,b,c,0,0,0)

__device__ __forceinline__ unsigned short f2bf(float f) {
  unsigned int u = __float_as_uint(f);
  unsigned int r = (u + 0x7fffu + ((u >> 16) & 1u)) >> 16;
  return (unsigned short)r;
}

// ---------------------------------------------------------------------------
// K1: node projections via MFMA. grid (25, 4), block 256. 128 nodes/block.
//   blockIdx.y: 0 -> WA -> A, 1 -> WB -> Bv, 2 -> WU -> h_in, 3 -> WV -> h_nb
// C[3200][128] = h[3200][128] @ W^T[128][128], K=128.
// ---------------------------------------------------------------------------
__global__ __launch_bounds__(256) void k1_proj(
    const float* __restrict__ h,
    const float* __restrict__ WA, const float* __restrict__ WB,
    const float* __restrict__ WU, const float* __restrict__ WV,
    float* __restrict__ ws) {
  __shared__ unsigned short h_lds[128 * 136];   // 34.8 KB, pad row to 136
  __shared__ unsigned short w_lds[128 * 136];   // 34.8 KB
  const int t  = threadIdx.x;
  const int r0 = blockIdx.x * 128;

  const float* W;
  float* outp;
  switch (blockIdx.y) {
    case 0:  W = WA; outp = ws + WS_A;   break;
    case 1:  W = WB; outp = ws + WS_BV;  break;
    case 2:  W = WU; outp = ws + WS_HIN; break;
    default: W = WV; outp = ws + WS_HNB; break;
  }

  const float4* hp = (const float4*)(h + (size_t)r0 * 128);
  const float4* wp = (const float4*)W;
#pragma unroll
  for (int k = 0; k < 16; ++k) {        // 4096 float4 each
    int i = t + k * 256;
    int row = i >> 5, col = (i & 31) * 4;
    float4 v = hp[i];
    ushort4 pk = make_ushort4(f2bf(v.x), f2bf(v.y), f2bf(v.z), f2bf(v.w));
    *(ushort4*)&h_lds[row * 136 + col] = pk;
    float4 u = wp[i];
    ushort4 qk = make_ushort4(f2bf(u.x), f2bf(u.y), f2bf(u.z), f2bf(u.w));
    *(ushort4*)&w_lds[row * 136 + col] = qk;
  }
  __syncthreads();

  const int w  = t >> 6;     // wave 0..3 -> d columns [32w, 32w+32)
  const int l  = t & 63;
  const int lr = l & 15;
  const int lg = l >> 4;

  bf16x8 bfr[2][4];
#pragma unroll
  for (int nt = 0; nt < 2; ++nt) {
    int d = w * 32 + nt * 16 + lr;
#pragma unroll
    for (int kb = 0; kb < 4; ++kb)
      bfr[nt][kb] = *(const bf16x8*)&w_lds[d * 136 + kb * 32 + lg * 8];
  }

  f32x4 acc[8][2];
#pragma unroll
  for (int mt = 0; mt < 8; ++mt)
#pragma unroll
    for (int nt = 0; nt < 2; ++nt) acc[mt][nt] = (f32x4)0.f;

#pragma unroll
  for (int mt = 0; mt < 8; ++mt) {
    int row = mt * 16 + lr;
    bf16x8 af[4];
#pragma unroll
    for (int kb = 0; kb < 4; ++kb)
      af[kb] = *(const bf16x8*)&h_lds[row * 136 + kb * 32 + lg * 8];
#pragma unroll
    for (int nt = 0; nt < 2; ++nt)
#pragma unroll
      for (int kb = 0; kb < 4; ++kb)
        acc[mt][nt] = MFMA16(af[kb], bfr[nt][kb], acc[mt][nt]);
  }

#pragma unroll
  for (int mt = 0; mt < 8; ++mt)
#pragma unroll
    for (int nt = 0; nt < 2; ++nt) {
      int dcol = w * 32 + nt * 16 + lr;
#pragma unroll
      for (int j = 0; j < 4; ++j) {
        int row = r0 + mt * 16 + lg * 4 + j;
        outp[row * 128 + dcol] = acc[mt][nt][j];
      }
    }
}

// ---------------------------------------------------------------------------
// K2: edge BN stats via MFMA. grid 3200 (one per (b,m)), block 256.
// eh_pre[n][d] = e[n,:]·WC[d,:] + A[b,m,d] + Bv[b,n,d]; accumulate sum/sumsq.
// ---------------------------------------------------------------------------
__global__ __launch_bounds__(256) void k2_stats(
    const float* __restrict__ e, const float* __restrict__ WC,
    float* __restrict__ ws) {
  __shared__ unsigned short e_lds[112 * 72];    // 16.1 KB (rows 100..111 zero)
  __shared__ unsigned short wc_lds[128 * 72];   // 18.4 KB
  const int t  = threadIdx.x;
  const int bm = blockIdx.x;
  const int b  = bm / N_;

  const float4* ep = (const float4*)(e + (size_t)bm * (N_ * ED_));
#pragma unroll
  for (int k = 0; k < 7; ++k) {         // 1600 float4 (last iter partial)
    int i = t + k * 256;
    if (i < 1600) {
      float4 v = ep[i];
      int row = i >> 4, col = (i & 15) * 4;
      ushort4 pk = make_ushort4(f2bf(v.x), f2bf(v.y), f2bf(v.z), f2bf(v.w));
      *(ushort4*)&e_lds[row * 72 + col] = pk;
    }
  }
  for (int i = t; i < 12 * 72; i += 256) e_lds[100 * 72 + i] = 0;  // zero pad rows
  const float4* wcp = (const float4*)WC;
#pragma unroll
  for (int k = 0; k < 8; ++k) {         // 2048 float4
    int i = t + k * 256;
    float4 v = wcp[i];
    int row = i >> 4, col = (i & 15) * 4;
    ushort4 pk = make_ushort4(f2bf(v.x), f2bf(v.y), f2bf(v.z), f2bf(v.w));
    *(ushort4*)&wc_lds[row * 72 + col] = pk;
  }
  __syncthreads();

  const int w  = t >> 6;
  const int l  = t & 63;
  const int lr = l & 15;
  const int lg = l >> 4;

  bf16x8 bfr[2][2];
#pragma unroll
  for (int nt = 0; nt < 2; ++nt) {
    int d = w * 32 + nt * 16 + lr;
#pragma unroll
    for (int kb = 0; kb < 2; ++kb)
      bfr[nt][kb] = *(const bf16x8*)&wc_lds[d * 72 + kb * 32 + lg * 8];
  }

  f32x4 acc[7][2];
#pragma unroll
  for (int mt = 0; mt < 7; ++mt) { acc[mt][0] = (f32x4)0.f; acc[mt][1] = (f32x4)0.f; }

#pragma unroll
  for (int mt = 0; mt < 7; ++mt) {
    int row = mt * 16 + lr;
    bf16x8 af0 = *(const bf16x8*)&e_lds[row * 72 + lg * 8];
    bf16x8 af1 = *(const bf16x8*)&e_lds[row * 72 + 32 + lg * 8];
#pragma unroll
    for (int nt = 0; nt < 2; ++nt) {
      acc[mt][nt] = MFMA16(af0, bfr[nt][0], acc[mt][nt]);
      acc[mt][nt] = MFMA16(af1, bfr[nt][1], acc[mt][nt]);
    }
  }

  const int d0 = w * 32 + lr, d1 = d0 + 16;
  const float A0 = ws[WS_A + bm * 128 + d0];
  const float A1 = ws[WS_A + bm * 128 + d1];
  const float* bvp = ws + WS_BV + b * (N_ * 128);

  float s0 = 0.f, ss0 = 0.f, s1 = 0.f, ss1 = 0.f;
#pragma unroll
  for (int mt = 0; mt < 7; ++mt)
#pragma unroll
    for (int j = 0; j < 4; ++j) {
      int node = mt * 16 + lg * 4 + j;
      if (node < N_) {
        float x0 = acc[mt][0][j] + A0 + bvp[node * 128 + d0];
        float x1 = acc[mt][1][j] + A1 + bvp[node * 128 + d1];
        s0 += x0; ss0 += x0 * x0;
        s1 += x1; ss1 += x1 * x1;
      }
    }
  s0 += __shfl_xor(s0, 16);  s0 += __shfl_xor(s0, 32);
  ss0 += __shfl_xor(ss0, 16); ss0 += __shfl_xor(ss0, 32);
  s1 += __shfl_xor(s1, 16);  s1 += __shfl_xor(s1, 32);
  ss1 += __shfl_xor(ss1, 16); ss1 += __shfl_xor(ss1, 32);
  if (l < 16) {
    atomicAdd(&ws[WS_STATS + b * 256 + d0], s0);
    atomicAdd(&ws[WS_STATS + b * 256 + 128 + d0], ss0);
    atomicAdd(&ws[WS_STATS + b * 256 + d1], s1);
    atomicAdd(&ws[WS_STATS + b * 256 + 128 + d1], ss1);
  }
}

// ---------------------------------------------------------------------------
// K4: main fused pass via MFMA. grid 3200, block 256.
// GEMM -> +A+Bv -> BN -> relu -> *adj -> sigmoid -> exp -> softmax over n
// -> write e_norm, aggregate m = sum_n e_norm * h_nb.
// ---------------------------------------------------------------------------
__global__ __launch_bounds__(256) void k4_main(
    const float* __restrict__ e, const float* __restrict__ adj,
    const float* __restrict__ WC,
    const float* __restrict__ gamma_e, const float* __restrict__ beta_e,
    float* __restrict__ ws, float* __restrict__ out_enorm) {
  __shared__ unsigned short e_lds[112 * 72];
  __shared__ unsigned short wc_lds[128 * 72];
  __shared__ float adj_lds[N_];
  __shared__ float sc_lds[128], sh_lds[128];
  const int t  = threadIdx.x;
  const int bm = blockIdx.x;
  const int b  = bm / N_;

  const float4* ep = (const float4*)(e + (size_t)bm * (N_ * ED_));
#pragma unroll
  for (int k = 0; k < 7; ++k) {
    int i = t + k * 256;
    if (i < 1600) {
      float4 v = ep[i];
      int row = i >> 4, col = (i & 15) * 4;
      ushort4 pk = make_ushort4(f2bf(v.x), f2bf(v.y), f2bf(v.z), f2bf(v.w));
      *(ushort4*)&e_lds[row * 72 + col] = pk;
    }
  }
  for (int i = t; i < 12 * 72; i += 256) e_lds[100 * 72 + i] = 0;
  const float4* wcp = (const float4*)WC;
#pragma unroll
  for (int k = 0; k < 8; ++k) {
    int i = t + k * 256;
    float4 v = wcp[i];
    int row = i >> 4, col = (i & 15) * 4;
    ushort4 pk = make_ushort4(f2bf(v.x), f2bf(v.y), f2bf(v.z), f2bf(v.w));
    *(ushort4*)&wc_lds[row * 72 + col] = pk;
  }
  if (t < N_) adj_lds[t] = adj[bm * N_ + t];
  if (t < 128) {
    float S = 0.f, SS = 0.f;
#pragma unroll
    for (int j = 0; j < 32; ++j) {
      S  += ws[WS_STATS + j * 256 + t];
      SS += ws[WS_STATS + j * 256 + 128 + t];
    }
    float mean = S * (1.0f / EDGE_SAMPLES);
    float var  = SS * (1.0f / EDGE_SAMPLES) - mean * mean;
    float sc   = gamma_e[t] * rsqrtf(var + EPS_);
    sc_lds[t] = sc;
    sh_lds[t] = beta_e[t] - mean * sc;
  }
  __syncthreads();

  const int w  = t >> 6;
  const int l  = t & 63;
  const int lr = l & 15;
  const int lg = l >> 4;

  bf16x8 bfr[2][2];
#pragma unroll
  for (int nt = 0; nt < 2; ++nt) {
    int d = w * 32 + nt * 16 + lr;
#pragma unroll
    for (int kb = 0; kb < 2; ++kb)
      bfr[nt][kb] = *(const bf16x8*)&wc_lds[d * 72 + kb * 32 + lg * 8];
  }

  f32x4 acc[7][2];
#pragma unroll
  for (int mt = 0; mt < 7; ++mt) { acc[mt][0] = (f32x4)0.f; acc[mt][1] = (f32x4)0.f; }

#pragma unroll
  for (int mt = 0; mt < 7; ++mt) {
    int row = mt * 16 + lr;
    bf16x8 af0 = *(const bf16x8*)&e_lds[row * 72 + lg * 8];
    bf16x8 af1 = *(const bf16x8*)&e_lds[row * 72 + 32 + lg * 8];
#pragma unroll
    for (int nt = 0; nt < 2; ++nt) {
      acc[mt][nt] = MFMA16(af0, bfr[nt][0], acc[mt][nt]);
      acc[mt][nt] = MFMA16(af1, bfr[nt][1], acc[mt][nt]);
    }
  }

  const int d0 = w * 32 + lr, d1 = d0 + 16;
  const float A0 = ws[WS_A + bm * 128 + d0];
  const float A1 = ws[WS_A + bm * 128 + d1];
  const float sc0 = sc_lds[d0], sh0 = sh_lds[d0];
  const float sc1 = sc_lds[d1], sh1 = sh_lds[d1];
  const float* bvp = ws + WS_BV + b * (N_ * 128);
  const float* hnp = ws + WS_HNB + b * (N_ * 128);

  // nonlinearity: p = exp(sigmoid(relu(bn(x)) * adj)); acc := p
  float den0 = 0.f, den1 = 0.f;
#pragma unroll
  for (int mt = 0; mt < 7; ++mt)
#pragma unroll
    for (int j = 0; j < 4; ++j) {
      int node = mt * 16 + lg * 4 + j;
      if (node < N_) {
        float adjv = adj_lds[node];
        float x0 = (acc[mt][0][j] + A0 + bvp[node * 128 + d0]) * sc0 + sh0;
        float x1 = (acc[mt][1][j] + A1 + bvp[node * 128 + d1]) * sc1 + sh1;
        x0 = fmaxf(x0, 0.f) * adjv;
        x1 = fmaxf(x1, 0.f) * adjv;
        float p0 = __expf(1.f / (1.f + __expf(-x0)));
        float p1 = __expf(1.f / (1.f + __expf(-x1)));
        acc[mt][0][j] = p0; den0 += p0;
        acc[mt][1][j] = p1; den1 += p1;
      } else {
        acc[mt][0][j] = 0.f; acc[mt][1][j] = 0.f;
      }
    }
  den0 += __shfl_xor(den0, 16); den0 += __shfl_xor(den0, 32);
  den1 += __shfl_xor(den1, 16); den1 += __shfl_xor(den1, 32);
  const float r0 = 1.f / den0, r1 = 1.f / den1;

  float msg0 = 0.f, msg1 = 0.f;
  float* outp = out_enorm + (size_t)bm * (N_ * 128);
#pragma unroll
  for (int mt = 0; mt < 7; ++mt)
#pragma unroll
    for (int j = 0; j < 4; ++j) {
      int node = mt * 16 + lg * 4 + j;
      if (node < N_) {
        float v0 = acc[mt][0][j] * r0;
        float v1 = acc[mt][1][j] * r1;
        outp[node * 128 + d0] = v0;
        outp[node * 128 + d1] = v1;
        msg0 += v0 * hnp[node * 128 + d0];
        msg1 += v1 * hnp[node * 128 + d1];
      }
    }
  msg0 += __shfl_xor(msg0, 16); msg0 += __shfl_xor(msg0, 32);
  msg1 += __shfl_xor(msg1, 16); msg1 += __shfl_xor(msg1, 32);
  if (l < 16) {
    ws[WS_M + bm * 128 + d0] = msg0;
    ws[WS_M + bm * 128 + d1] = msg1;
  }
}

// ---------------------------------------------------------------------------
// K5a: node BN statistics over m [3200][128]. grid 32, block 256.
// ---------------------------------------------------------------------------
__global__ __launch_bounds__(256) void k5a_nstats(float* __restrict__ ws) {
  __shared__ float red[256];
  const int t = threadIdx.x;
  const int j = blockIdx.x;
  const int d = t & 127, rh = t >> 7;
  float s = 0.f, sssum = 0.f;
  for (int r = j * 100 + rh; r < (j + 1) * 100; r += 2) {
    float v = ws[WS_M + r * 128 + d];
    s += v;
    sssum += v * v;
  }
  red[t] = s;
  __syncthreads();
  if (t < 128) atomicAdd(&ws[WS_NSTATS + t], red[t] + red[t + 128]);
  __syncthreads();
  red[t] = sssum;
  __syncthreads();
  if (t < 128) atomicAdd(&ws[WS_NSTATS + 128 + t], red[t] + red[t + 128]);
}

// ---------------------------------------------------------------------------
// K5b: h_out = h_in + relu(bn_node(m)). grid 1600, block 256.
// ---------------------------------------------------------------------------
__global__ __launch_bounds__(256) void k5b_hout(
    const float* __restrict__ gamma_n, const float* __restrict__ beta_n,
    const float* __restrict__ ws, float* __restrict__ hout) {
  const int idx = blockIdx.x * 256 + threadIdx.x;
  const int d = idx & 127;
  float S  = ws[WS_NSTATS + d];
  float SS = ws[WS_NSTATS + 128 + d];
  float mean = S * (1.0f / (float)NNODE);
  float var  = SS * (1.0f / (float)NNODE) - mean * mean;
  float sc   = gamma_n[d] * rsqrtf(var + EPS_);
  float sh   = beta_n[d] - mean * sc;
  float mv   = ws[WS_M + idx];
  hout[idx]  = ws[WS_HIN + idx] + fmaxf(mv * sc + sh, 0.f);
}

// ---------------------------------------------------------------------------
extern "C" void kernel_launch(void* const* d_in, const int* in_sizes, int n_in,
                              void* d_out, int out_size, void* d_ws, size_t ws_size,
                              hipStream_t stream) {
  (void)in_sizes; (void)n_in; (void)out_size; (void)ws_size;
  const float* h   = (const float*)d_in[0];
  const float* e   = (const float*)d_in[1];
  const float* adj = (const float*)d_in[2];
  const float* WU  = (const float*)d_in[3];
  const float* WV  = (const float*)d_in[4];
  const float* WA  = (const float*)d_in[5];
  const float* WB  = (const float*)d_in[6];
  const float* WC  = (const float*)d_in[7];
  const float* geg = (const float*)d_in[8];
  const float* geb = (const float*)d_in[9];
  const float* gng = (const float*)d_in[10];
  const float* gnb = (const float*)d_in[11];

  float* out = (float*)d_out;   // h_out [409600] then e_norm [40960000]
  float* ws  = (float*)d_ws;

  hipMemsetAsync(ws + WS_STATS, 0, (8192 + 256) * sizeof(float), stream);

  k1_proj   <<<dim3(25, 4), 256, 0, stream>>>(h, WA, WB, WU, WV, ws);
  k2_stats  <<<3200,        256, 0, stream>>>(e, WC, ws);
  k4_main   <<<3200,        256, 0, stream>>>(e, adj, WC, geg, geb, ws, out + 409600);
  k5a_nstats<<<32,          256, 0, stream>>>(ws);
  k5b_hout  <<<1600,        256, 0, stream>>>(gng, gnb, ws, out);
}

// Round 5
// 130.471 us; speedup vs baseline: 2.9620x; 1.1846x over previous
//
#include <hip/hip_runtime.h>
#include <math.h>

// Problem constants
#define B_   32
#define N_   100
#define ND_  128   // NODE_DIM
#define ED_  64    // EDGE_DIM
#define HID_ 128
#define EPS_ 1e-5f
#define NNODE (B_*N_)                 // 3200
#define EDGE_SAMPLES ((float)(B_*N_*N_))  // 320000

#define MC_     7                     // m-rows per block
#define CHUNKS_ 15                    // ceil(100/7)

// Workspace layout (in floats)
#define WS_A      0          // A  = h @ WA^T   [3200][128]
#define WS_BV     409600     // Bv = h @ WB^T   [3200][128]
#define WS_HIN    819200     // h_in = h @ WU^T [3200][128]
#define WS_HNB    1228800    // h_nb = h @ WV^T [3200][128]
#define WS_M      1638400    // m aggregation   [3200][128]
#define WS_STATS  2048000    // edge BN stats [32][2][128] = 8192 floats (atomics)
#define WS_SCSH   2056192    // finalized edge BN scale/shift [2][128]
#define WS_NSTATS 2056448    // node BN stats [2][128]
// total 2056704 floats (same footprint as the previous working round)

typedef __attribute__((ext_vector_type(8))) short bf16x8;
typedef __attribute__((ext_vector_type(4))) float f32x4;
#define MFMA16(a,b,c) __builtin_amdgcn_mfma_f32_16x16x32_bf16(a,b,c,0,0,0)

__device__ __forceinline__ unsigned short f2bf(float f) {
  unsigned int u = __float_as_uint(f);
  unsigned int r = (u + 0x7fffu + ((u >> 16) & 1u)) >> 16;
  return (unsigned short)r;
}

// ---------------------------------------------------------------------------
// K1: node projections via MFMA. grid (25, 4), block 256. 128 nodes/block.
// ---------------------------------------------------------------------------
__global__ __launch_bounds__(256) void k1_proj(
    const float* __restrict__ h,
    const float* __restrict__ WA, const float* __restrict__ WB,
    const float* __restrict__ WU, const float* __restrict__ WV,
    float* __restrict__ ws) {
  __shared__ unsigned short h_lds[128 * 136];
  __shared__ unsigned short w_lds[128 * 136];
  const int t  = threadIdx.x;
  const int r0 = blockIdx.x * 128;

  const float* W;
  float* outp;
  switch (blockIdx.y) {
    case 0:  W = WA; outp = ws + WS_A;   break;
    case 1:  W = WB; outp = ws + WS_BV;  break;
    case 2:  W = WU; outp = ws + WS_HIN; break;
    default: W = WV; outp = ws + WS_HNB; break;
  }

  const float4* hp = (const float4*)(h + (size_t)r0 * 128);
  const float4* wp = (const float4*)W;
#pragma unroll
  for (int k = 0; k < 16; ++k) {
    int i = t + k * 256;
    int row = i >> 5, col = (i & 31) * 4;
    float4 v = hp[i];
    *(ushort4*)&h_lds[row * 136 + col] =
        make_ushort4(f2bf(v.x), f2bf(v.y), f2bf(v.z), f2bf(v.w));
    float4 u = wp[i];
    *(ushort4*)&w_lds[row * 136 + col] =
        make_ushort4(f2bf(u.x), f2bf(u.y), f2bf(u.z), f2bf(u.w));
  }
  __syncthreads();

  const int w  = t >> 6;
  const int l  = t & 63;
  const int lr = l & 15;
  const int lg = l >> 4;

  bf16x8 bfr[2][4];
#pragma unroll
  for (int nt = 0; nt < 2; ++nt) {
    int d = w * 32 + nt * 16 + lr;
#pragma unroll
    for (int kb = 0; kb < 4; ++kb)
      bfr[nt][kb] = *(const bf16x8*)&w_lds[d * 136 + kb * 32 + lg * 8];
  }

  f32x4 acc[8][2];
#pragma unroll
  for (int mt = 0; mt < 8; ++mt) { acc[mt][0] = (f32x4)0.f; acc[mt][1] = (f32x4)0.f; }

#pragma unroll
  for (int mt = 0; mt < 8; ++mt) {
    int row = mt * 16 + lr;
    bf16x8 af[4];
#pragma unroll
    for (int kb = 0; kb < 4; ++kb)
      af[kb] = *(const bf16x8*)&h_lds[row * 136 + kb * 32 + lg * 8];
#pragma unroll
    for (int nt = 0; nt < 2; ++nt)
#pragma unroll
      for (int kb = 0; kb < 4; ++kb)
        acc[mt][nt] = MFMA16(af[kb], bfr[nt][kb], acc[mt][nt]);
  }

#pragma unroll
  for (int mt = 0; mt < 8; ++mt)
#pragma unroll
    for (int nt = 0; nt < 2; ++nt) {
      int dcol = w * 32 + nt * 16 + lr;
#pragma unroll
      for (int j = 0; j < 4; ++j) {
        int row = r0 + mt * 16 + lg * 4 + j;
        outp[row * 128 + dcol] = acc[mt][nt][j];
      }
    }
}

// ---------------------------------------------------------------------------
// K2: edge BN stats. grid (32, 15), block 256. Each block: one b, MC_ m-rows.
// Bv held in registers (row-invariant); e rows double-buffered through LDS.
// ---------------------------------------------------------------------------
__global__ __launch_bounds__(256, 1) void k2_stats(
    const float* __restrict__ e, const float* __restrict__ WC,
    float* __restrict__ ws) {
  __shared__ unsigned short wc_lds[128 * 72];
  __shared__ unsigned short e_lds[2][112 * 72];
  const int t     = threadIdx.x;
  const int b     = blockIdx.x;
  const int chunk = blockIdx.y;
  const int m0    = chunk * MC_;
  const int mcnt  = min(MC_, N_ - m0);

  const float4* wcp = (const float4*)WC;
#pragma unroll
  for (int k = 0; k < 8; ++k) {
    int i = t + k * 256;
    float4 v = wcp[i];
    int row = i >> 4, col = (i & 15) * 4;
    *(ushort4*)&wc_lds[row * 72 + col] =
        make_ushort4(f2bf(v.x), f2bf(v.y), f2bf(v.z), f2bf(v.w));
  }
  for (int i = t; i < 12 * 72; i += 256) {   // zero pad rows of both buffers
    e_lds[0][100 * 72 + i] = 0;
    e_lds[1][100 * 72 + i] = 0;
  }

  const int w  = t >> 6;
  const int l  = t & 63;
  const int lr = l & 15;
  const int lg = l >> 4;
  const int d0 = w * 32 + lr, d1 = d0 + 16;

  // Bv registers: row-invariant scattered loads, once per block
  float bvr[7][4][2];
  const float* bvp = ws + WS_BV + b * (N_ * 128);
#pragma unroll
  for (int mt = 0; mt < 7; ++mt)
#pragma unroll
    for (int j = 0; j < 4; ++j) {
      int node = mt * 16 + lg * 4 + j;
      bool ok = node < N_;
      bvr[mt][j][0] = ok ? bvp[node * 128 + d0] : 0.f;
      bvr[mt][j][1] = ok ? bvp[node * 128 + d1] : 0.f;
    }
  __syncthreads();

  bf16x8 bfr[2][2];
#pragma unroll
  for (int nt = 0; nt < 2; ++nt) {
    int d = w * 32 + nt * 16 + lr;
#pragma unroll
    for (int kb = 0; kb < 2; ++kb)
      bfr[nt][kb] = *(const bf16x8*)&wc_lds[d * 72 + kb * 32 + lg * 8];
  }

  // prologue: load row m0 into regs
  float4 ld[7];
  {
    const float4* epf4 = (const float4*)(e + (size_t)(b * N_ + m0) * (N_ * ED_));
#pragma unroll
    for (int k = 0; k < 7; ++k) { int i = t + k * 256; if (i < 1600) ld[k] = epf4[i]; }
  }

  float s0 = 0.f, ss0 = 0.f, s1 = 0.f, ss1 = 0.f;
  int buf = 0;
  for (int r = 0; r < mcnt; ++r) {
    // write phase: regs -> LDS (bf16)
#pragma unroll
    for (int k = 0; k < 7; ++k) {
      int i = t + k * 256;
      if (i < 1600) {
        float4 v = ld[k];
        int row = i >> 4, col = (i & 15) * 4;
        *(ushort4*)&e_lds[buf][row * 72 + col] =
            make_ushort4(f2bf(v.x), f2bf(v.y), f2bf(v.z), f2bf(v.w));
      }
    }
    __syncthreads();
    // issue next-row loads early (hide under compute)
    if (r + 1 < mcnt) {
      const float4* nxt = (const float4*)(e + (size_t)(b * N_ + m0 + r + 1) * (N_ * ED_));
#pragma unroll
      for (int k = 0; k < 7; ++k) { int i = t + k * 256; if (i < 1600) ld[k] = nxt[i]; }
    }

    const int bm = b * N_ + m0 + r;
    const float A0 = ws[WS_A + bm * 128 + d0];
    const float A1 = ws[WS_A + bm * 128 + d1];

    f32x4 acc[7][2];
#pragma unroll
    for (int mt = 0; mt < 7; ++mt) { acc[mt][0] = (f32x4)0.f; acc[mt][1] = (f32x4)0.f; }
#pragma unroll
    for (int mt = 0; mt < 7; ++mt) {
      int row = mt * 16 + lr;
      bf16x8 af0 = *(const bf16x8*)&e_lds[buf][row * 72 + lg * 8];
      bf16x8 af1 = *(const bf16x8*)&e_lds[buf][row * 72 + 32 + lg * 8];
#pragma unroll
      for (int nt = 0; nt < 2; ++nt) {
        acc[mt][nt] = MFMA16(af0, bfr[nt][0], acc[mt][nt]);
        acc[mt][nt] = MFMA16(af1, bfr[nt][1], acc[mt][nt]);
      }
    }

#pragma unroll
    for (int mt = 0; mt < 7; ++mt)
#pragma unroll
      for (int j = 0; j < 4; ++j) {
        int node = mt * 16 + lg * 4 + j;
        if (node < N_) {
          float x0 = acc[mt][0][j] + A0 + bvr[mt][j][0];
          float x1 = acc[mt][1][j] + A1 + bvr[mt][j][1];
          s0 += x0; ss0 += x0 * x0;
          s1 += x1; ss1 += x1 * x1;
        }
      }
    buf ^= 1;
  }

  s0 += __shfl_xor(s0, 16);  s0 += __shfl_xor(s0, 32);
  ss0 += __shfl_xor(ss0, 16); ss0 += __shfl_xor(ss0, 32);
  s1 += __shfl_xor(s1, 16);  s1 += __shfl_xor(s1, 32);
  ss1 += __shfl_xor(ss1, 16); ss1 += __shfl_xor(ss1, 32);
  if (l < 16) {
    atomicAdd(&ws[WS_STATS + b * 256 + d0], s0);
    atomicAdd(&ws[WS_STATS + b * 256 + 128 + d0], ss0);
    atomicAdd(&ws[WS_STATS + b * 256 + d1], s1);
    atomicAdd(&ws[WS_STATS + b * 256 + 128 + d1], ss1);
  }
}

// ---------------------------------------------------------------------------
// K0: finalize edge BN -> scale/shift (one block, 128 threads)
// ---------------------------------------------------------------------------
__global__ __launch_bounds__(128) void k0_finalize(
    const float* __restrict__ gamma_e, const float* __restrict__ beta_e,
    float* __restrict__ ws) {
  const int t = threadIdx.x;   // 0..127
  float S = 0.f, SS = 0.f;
#pragma unroll
  for (int j = 0; j < 32; ++j) {
    S  += ws[WS_STATS + j * 256 + t];
    SS += ws[WS_STATS + j * 256 + 128 + t];
  }
  float mean = S * (1.0f / EDGE_SAMPLES);
  float var  = SS * (1.0f / EDGE_SAMPLES) - mean * mean;
  float sc   = gamma_e[t] * rsqrtf(var + EPS_);
  ws[WS_SCSH + t]       = sc;
  ws[WS_SCSH + 128 + t] = beta_e[t] - mean * sc;
}

// ---------------------------------------------------------------------------
// K4: main fused pass. grid (32, 15), block 256. One b, MC_ m-rows per block.
// Bv + hnb in registers; e rows + adj double-buffered in LDS.
// ---------------------------------------------------------------------------
__global__ __launch_bounds__(256, 1) void k4_main(
    const float* __restrict__ e, const float* __restrict__ adj,
    const float* __restrict__ WC,
    float* __restrict__ ws, float* __restrict__ out_enorm) {
  __shared__ unsigned short wc_lds[128 * 72];
  __shared__ unsigned short e_lds[2][112 * 72];
  __shared__ float adj_lds[2][112];
  const int t     = threadIdx.x;
  const int b     = blockIdx.x;
  const int chunk = blockIdx.y;
  const int m0    = chunk * MC_;
  const int mcnt  = min(MC_, N_ - m0);

  const float4* wcp = (const float4*)WC;
#pragma unroll
  for (int k = 0; k < 8; ++k) {
    int i = t + k * 256;
    float4 v = wcp[i];
    int row = i >> 4, col = (i & 15) * 4;
    *(ushort4*)&wc_lds[row * 72 + col] =
        make_ushort4(f2bf(v.x), f2bf(v.y), f2bf(v.z), f2bf(v.w));
  }
  for (int i = t; i < 12 * 72; i += 256) {
    e_lds[0][100 * 72 + i] = 0;
    e_lds[1][100 * 72 + i] = 0;
  }

  const int w  = t >> 6;
  const int l  = t & 63;
  const int lr = l & 15;
  const int lg = l >> 4;
  const int d0 = w * 32 + lr, d1 = d0 + 16;

  const float sc0 = ws[WS_SCSH + d0], sh0 = ws[WS_SCSH + 128 + d0];
  const float sc1 = ws[WS_SCSH + d1], sh1 = ws[WS_SCSH + 128 + d1];

  // Bv + hnb registers (row-invariant)
  float bvr[7][4][2], hnr[7][4][2];
  const float* bvp = ws + WS_BV  + b * (N_ * 128);
  const float* hnp = ws + WS_HNB + b * (N_ * 128);
#pragma unroll
  for (int mt = 0; mt < 7; ++mt)
#pragma unroll
    for (int j = 0; j < 4; ++j) {
      int node = mt * 16 + lg * 4 + j;
      bool ok = node < N_;
      bvr[mt][j][0] = ok ? bvp[node * 128 + d0] : 0.f;
      bvr[mt][j][1] = ok ? bvp[node * 128 + d1] : 0.f;
      hnr[mt][j][0] = ok ? hnp[node * 128 + d0] : 0.f;
      hnr[mt][j][1] = ok ? hnp[node * 128 + d1] : 0.f;
    }
  __syncthreads();

  bf16x8 bfr[2][2];
#pragma unroll
  for (int nt = 0; nt < 2; ++nt) {
    int d = w * 32 + nt * 16 + lr;
#pragma unroll
    for (int kb = 0; kb < 2; ++kb)
      bfr[nt][kb] = *(const bf16x8*)&wc_lds[d * 72 + kb * 32 + lg * 8];
  }

  // prologue: load row m0
  float4 ld[7];
  float adjreg = 0.f;
  {
    const float4* epf4 = (const float4*)(e + (size_t)(b * N_ + m0) * (N_ * ED_));
#pragma unroll
    for (int k = 0; k < 7; ++k) { int i = t + k * 256; if (i < 1600) ld[k] = epf4[i]; }
    if (t < N_) adjreg = adj[(b * N_ + m0) * N_ + t];
  }

  int buf = 0;
  for (int r = 0; r < mcnt; ++r) {
#pragma unroll
    for (int k = 0; k < 7; ++k) {
      int i = t + k * 256;
      if (i < 1600) {
        float4 v = ld[k];
        int row = i >> 4, col = (i & 15) * 4;
        *(ushort4*)&e_lds[buf][row * 72 + col] =
            make_ushort4(f2bf(v.x), f2bf(v.y), f2bf(v.z), f2bf(v.w));
      }
    }
    if (t < N_) adj_lds[buf][t] = adjreg;
    __syncthreads();

    if (r + 1 < mcnt) {
      const float4* nxt = (const float4*)(e + (size_t)(b * N_ + m0 + r + 1) * (N_ * ED_));
#pragma unroll
      for (int k = 0; k < 7; ++k) { int i = t + k * 256; if (i < 1600) ld[k] = nxt[i]; }
      if (t < N_) adjreg = adj[(b * N_ + m0 + r + 1) * N_ + t];
    }

    const int bm = b * N_ + m0 + r;
    const float A0 = ws[WS_A + bm * 128 + d0];
    const float A1 = ws[WS_A + bm * 128 + d1];

    f32x4 acc[7][2];
#pragma unroll
    for (int mt = 0; mt < 7; ++mt) { acc[mt][0] = (f32x4)0.f; acc[mt][1] = (f32x4)0.f; }
#pragma unroll
    for (int mt = 0; mt < 7; ++mt) {
      int row = mt * 16 + lr;
      bf16x8 af0 = *(const bf16x8*)&e_lds[buf][row * 72 + lg * 8];
      bf16x8 af1 = *(const bf16x8*)&e_lds[buf][row * 72 + 32 + lg * 8];
#pragma unroll
      for (int nt = 0; nt < 2; ++nt) {
        acc[mt][nt] = MFMA16(af0, bfr[nt][0], acc[mt][nt]);
        acc[mt][nt] = MFMA16(af1, bfr[nt][1], acc[mt][nt]);
      }
    }

    // nonlinearity: p = exp(sigmoid(relu(bn(x)) * adj))
    float den0 = 0.f, den1 = 0.f;
#pragma unroll
    for (int mt = 0; mt < 7; ++mt)
#pragma unroll
      for (int j = 0; j < 4; ++j) {
        int node = mt * 16 + lg * 4 + j;
        if (node < N_) {
          float adjv = adj_lds[buf][node];
          float x0 = (acc[mt][0][j] + A0 + bvr[mt][j][0]) * sc0 + sh0;
          float x1 = (acc[mt][1][j] + A1 + bvr[mt][j][1]) * sc1 + sh1;
          x0 = fmaxf(x0, 0.f) * adjv;
          x1 = fmaxf(x1, 0.f) * adjv;
          float p0 = __expf(1.f / (1.f + __expf(-x0)));
          float p1 = __expf(1.f / (1.f + __expf(-x1)));
          acc[mt][0][j] = p0; den0 += p0;
          acc[mt][1][j] = p1; den1 += p1;
        }
      }
    den0 += __shfl_xor(den0, 16); den0 += __shfl_xor(den0, 32);
    den1 += __shfl_xor(den1, 16); den1 += __shfl_xor(den1, 32);
    const float rc0 = 1.f / den0, rc1 = 1.f / den1;

    float msg0 = 0.f, msg1 = 0.f;
    float* outp = out_enorm + (size_t)bm * (N_ * 128);
#pragma unroll
    for (int mt = 0; mt < 7; ++mt)
#pragma unroll
      for (int j = 0; j < 4; ++j) {
        int node = mt * 16 + lg * 4 + j;
        if (node < N_) {
          float v0 = acc[mt][0][j] * rc0;
          float v1 = acc[mt][1][j] * rc1;
          outp[node * 128 + d0] = v0;
          outp[node * 128 + d1] = v1;
          msg0 += v0 * hnr[mt][j][0];
          msg1 += v1 * hnr[mt][j][1];
        }
      }
    msg0 += __shfl_xor(msg0, 16); msg0 += __shfl_xor(msg0, 32);
    msg1 += __shfl_xor(msg1, 16); msg1 += __shfl_xor(msg1, 32);
    if (l < 16) {
      ws[WS_M + bm * 128 + d0] = msg0;
      ws[WS_M + bm * 128 + d1] = msg1;
    }
    buf ^= 1;
  }
}

// ---------------------------------------------------------------------------
// K5a: node BN statistics over m [3200][128]. grid 32, block 256.
// ---------------------------------------------------------------------------
__global__ __launch_bounds__(256) void k5a_nstats(float* __restrict__ ws) {
  __shared__ float red[256];
  const int t = threadIdx.x;
  const int j = blockIdx.x;
  const int d = t & 127, rh = t >> 7;
  float s = 0.f, sssum = 0.f;
  for (int r = j * 100 + rh; r < (j + 1) * 100; r += 2) {
    float v = ws[WS_M + r * 128 + d];
    s += v;
    sssum += v * v;
  }
  red[t] = s;
  __syncthreads();
  if (t < 128) atomicAdd(&ws[WS_NSTATS + t], red[t] + red[t + 128]);
  __syncthreads();
  red[t] = sssum;
  __syncthreads();
  if (t < 128) atomicAdd(&ws[WS_NSTATS + 128 + t], red[t] + red[t + 128]);
}

// ---------------------------------------------------------------------------
// K5b: h_out = h_in + relu(bn_node(m)). grid 1600, block 256.
// ---------------------------------------------------------------------------
__global__ __launch_bounds__(256) void k5b_hout(
    const float* __restrict__ gamma_n, const float* __restrict__ beta_n,
    const float* __restrict__ ws, float* __restrict__ hout) {
  const int idx = blockIdx.x * 256 + threadIdx.x;
  const int d = idx & 127;
  float S  = ws[WS_NSTATS + d];
  float SS = ws[WS_NSTATS + 128 + d];
  float mean = S * (1.0f / (float)NNODE);
  float var  = SS * (1.0f / (float)NNODE) - mean * mean;
  float sc   = gamma_n[d] * rsqrtf(var + EPS_);
  float sh   = beta_n[d] - mean * sc;
  float mv   = ws[WS_M + idx];
  hout[idx]  = ws[WS_HIN + idx] + fmaxf(mv * sc + sh, 0.f);
}

// ---------------------------------------------------------------------------
extern "C" void kernel_launch(void* const* d_in, const int* in_sizes, int n_in,
                              void* d_out, int out_size, void* d_ws, size_t ws_size,
                              hipStream_t stream) {
  (void)in_sizes; (void)n_in; (void)out_size; (void)ws_size;
  const float* h   = (const float*)d_in[0];
  const float* e   = (const float*)d_in[1];
  const float* adj = (const float*)d_in[2];
  const float* WU  = (const float*)d_in[3];
  const float* WV  = (const float*)d_in[4];
  const float* WA  = (const float*)d_in[5];
  const float* WB  = (const float*)d_in[6];
  const float* WC  = (const float*)d_in[7];
  const float* geg = (const float*)d_in[8];
  const float* geb = (const float*)d_in[9];
  const float* gng = (const float*)d_in[10];
  const float* gnb = (const float*)d_in[11];

  float* out = (float*)d_out;   // h_out [409600] then e_norm [40960000]
  float* ws  = (float*)d_ws;

  // zero the atomic accumulators (STATS + SCSH + NSTATS region)
  hipMemsetAsync(ws + WS_STATS, 0, (8192 + 512) * sizeof(float), stream);

  k1_proj    <<<dim3(25, 4),   256, 0, stream>>>(h, WA, WB, WU, WV, ws);
  k2_stats   <<<dim3(32, 15),  256, 0, stream>>>(e, WC, ws);
  k0_finalize<<<1,             128, 0, stream>>>(geg, geb, ws);
  k4_main    <<<dim3(32, 15),  256, 0, stream>>>(e, adj, WC, ws, out + 409600);
  k5a_nstats <<<32,            256, 0, stream>>>(ws);
  k5b_hout   <<<1600,          256, 0, stream>>>(gng, gnb, ws, out);
}

// Round 6
// 108.836 us; speedup vs baseline: 3.5508x; 1.1988x over previous
//
#include <hip/hip_runtime.h>
#include <math.h>

// Problem constants
#define B_   32
#define N_   100
#define ND_  128   // NODE_DIM
#define ED_  64    // EDGE_DIM
#define HID_ 128
#define EPS_ 1e-5f
#define NNODE (B_*N_)                 // 3200
#define EDGE_SAMPLES ((float)(B_*N_*N_))  // 320000

#define MC_     7                     // m-rows per block (k2)
#define CHUNKS_ 15                    // ceil(100/7)

// Workspace layout (in floats)
#define WS_A      0          // A  = h @ WA^T   [3200][128] f32
#define WS_PK     409600     // packed (bf16 Bv | bf16 hnb) [3200][128] uint
#define WS_HIN    819200     // h_in = h @ WU^T [3200][128] f32
#define WS_M      1638400    // m aggregation   [3200][128] f32
#define WS_STATS  2048000    // edge BN stats [32][2][128] = 8192 floats (atomics)
#define WS_SCSH   2056192    // finalized edge BN scale/shift [2][128]
#define WS_NSTATS 2056448    // node BN stats [2][128]

typedef __attribute__((ext_vector_type(8))) short bf16x8;
typedef __attribute__((ext_vector_type(4))) float f32x4;
#define MFMA16(a,b,c) __builtin_amdgcn_mfma_f32_16x16x32_bf16(a,b,c,0,0,0)

__device__ __forceinline__ unsigned short f2bf(float f) {
  unsigned int u = __float_as_uint(f);
  unsigned int r = (u + 0x7fffu + ((u >> 16) & 1u)) >> 16;
  return (unsigned short)r;
}

// ---------------------------------------------------------------------------
// K1: node projections via MFMA. grid (25, 4), block 256. 128 nodes/block.
//   y==0: WA -> WS_A (f32)        y==2: WU -> WS_HIN (f32)
//   y==1: WB -> WS_PK lo (bf16)   y==3: WV -> WS_PK hi (bf16)
// ---------------------------------------------------------------------------
__global__ __launch_bounds__(256) void k1_proj(
    const float* __restrict__ h,
    const float* __restrict__ WA, const float* __restrict__ WB,
    const float* __restrict__ WU, const float* __restrict__ WV,
    float* __restrict__ ws) {
  __shared__ unsigned short h_lds[128 * 136];
  __shared__ unsigned short w_lds[128 * 136];
  const int t  = threadIdx.x;
  const int r0 = blockIdx.x * 128;
  const int y  = blockIdx.y;
  const float* W = (y == 0) ? WA : (y == 1) ? WB : (y == 2) ? WU : WV;

  const float4* hp = (const float4*)(h + (size_t)r0 * 128);
  const float4* wp = (const float4*)W;
#pragma unroll
  for (int k = 0; k < 16; ++k) {
    int i = t + k * 256;
    int row = i >> 5, col = (i & 31) * 4;
    float4 v = hp[i];
    *(ushort4*)&h_lds[row * 136 + col] =
        make_ushort4(f2bf(v.x), f2bf(v.y), f2bf(v.z), f2bf(v.w));
    float4 u = wp[i];
    *(ushort4*)&w_lds[row * 136 + col] =
        make_ushort4(f2bf(u.x), f2bf(u.y), f2bf(u.z), f2bf(u.w));
  }
  __syncthreads();

  const int w  = t >> 6;
  const int l  = t & 63;
  const int lr = l & 15;
  const int lg = l >> 4;

  bf16x8 bfr[2][4];
#pragma unroll
  for (int nt = 0; nt < 2; ++nt) {
    int d = w * 32 + nt * 16 + lr;
#pragma unroll
    for (int kb = 0; kb < 4; ++kb)
      bfr[nt][kb] = *(const bf16x8*)&w_lds[d * 136 + kb * 32 + lg * 8];
  }

  f32x4 acc[8][2];
#pragma unroll
  for (int mt = 0; mt < 8; ++mt) { acc[mt][0] = (f32x4)0.f; acc[mt][1] = (f32x4)0.f; }

#pragma unroll
  for (int mt = 0; mt < 8; ++mt) {
    int row = mt * 16 + lr;
    bf16x8 af[4];
#pragma unroll
    for (int kb = 0; kb < 4; ++kb)
      af[kb] = *(const bf16x8*)&h_lds[row * 136 + kb * 32 + lg * 8];
#pragma unroll
    for (int nt = 0; nt < 2; ++nt)
#pragma unroll
      for (int kb = 0; kb < 4; ++kb)
        acc[mt][nt] = MFMA16(af[kb], bfr[nt][kb], acc[mt][nt]);
  }

  if (y == 0 || y == 2) {
    float* outp = ws + ((y == 0) ? WS_A : WS_HIN);
#pragma unroll
    for (int mt = 0; mt < 8; ++mt)
#pragma unroll
      for (int nt = 0; nt < 2; ++nt) {
        int dcol = w * 32 + nt * 16 + lr;
#pragma unroll
        for (int j = 0; j < 4; ++j) {
          int row = r0 + mt * 16 + lg * 4 + j;
          outp[row * 128 + dcol] = acc[mt][nt][j];
        }
      }
  } else {
    unsigned short* pks = (unsigned short*)(ws + WS_PK);
    const int half = (y == 1) ? 0 : 1;
#pragma unroll
    for (int mt = 0; mt < 8; ++mt)
#pragma unroll
      for (int nt = 0; nt < 2; ++nt) {
        int dcol = w * 32 + nt * 16 + lr;
#pragma unroll
        for (int j = 0; j < 4; ++j) {
          int row = r0 + mt * 16 + lg * 4 + j;
          pks[(row * 128 + dcol) * 2 + half] = f2bf(acc[mt][nt][j]);
        }
      }
  }
}

// ---------------------------------------------------------------------------
// K2: edge BN stats. grid (32, 15), block 256. One b, MC_ m-rows per block.
// Bv (bf16, from WS_PK lo) in registers; e rows double-buffered in LDS.
// ---------------------------------------------------------------------------
__global__ __launch_bounds__(256, 1) void k2_stats(
    const float* __restrict__ e, const float* __restrict__ WC,
    float* __restrict__ ws) {
  __shared__ unsigned short wc_lds[128 * 72];
  __shared__ unsigned short e_lds[2][112 * 72];
  const int t     = threadIdx.x;
  const int b     = blockIdx.x;
  const int chunk = blockIdx.y;
  const int m0    = chunk * MC_;
  const int mcnt  = min(MC_, N_ - m0);

  const float4* wcp = (const float4*)WC;
#pragma unroll
  for (int k = 0; k < 8; ++k) {
    int i = t + k * 256;
    float4 v = wcp[i];
    int row = i >> 4, col = (i & 15) * 4;
    *(ushort4*)&wc_lds[row * 72 + col] =
        make_ushort4(f2bf(v.x), f2bf(v.y), f2bf(v.z), f2bf(v.w));
  }
  for (int i = t; i < 12 * 72; i += 256) {
    e_lds[0][100 * 72 + i] = 0;
    e_lds[1][100 * 72 + i] = 0;
  }

  const int w  = t >> 6;
  const int l  = t & 63;
  const int lr = l & 15;
  const int lg = l >> 4;
  const int d0 = w * 32 + lr, d1 = d0 + 16;

  // Bv registers (bf16-unpacked, consistent with k4)
  float bvr[7][4][2];
  const unsigned int* pkp = (const unsigned int*)(ws + WS_PK) + b * (N_ * 128);
#pragma unroll
  for (int mt = 0; mt < 7; ++mt)
#pragma unroll
    for (int j = 0; j < 4; ++j) {
      int node = mt * 16 + lg * 4 + j;
      bool ok = node < N_;
      bvr[mt][j][0] = ok ? __uint_as_float(pkp[node * 128 + d0] << 16) : 0.f;
      bvr[mt][j][1] = ok ? __uint_as_float(pkp[node * 128 + d1] << 16) : 0.f;
    }
  __syncthreads();

  bf16x8 bfr[2][2];
#pragma unroll
  for (int nt = 0; nt < 2; ++nt) {
    int d = w * 32 + nt * 16 + lr;
#pragma unroll
    for (int kb = 0; kb < 2; ++kb)
      bfr[nt][kb] = *(const bf16x8*)&wc_lds[d * 72 + kb * 32 + lg * 8];
  }

  float4 ld[7];
  {
    const float4* epf4 = (const float4*)(e + (size_t)(b * N_ + m0) * (N_ * ED_));
#pragma unroll
    for (int k = 0; k < 7; ++k) { int i = t + k * 256; if (i < 1600) ld[k] = epf4[i]; }
  }

  float s0 = 0.f, ss0 = 0.f, s1 = 0.f, ss1 = 0.f;
  int buf = 0;
  for (int r = 0; r < mcnt; ++r) {
#pragma unroll
    for (int k = 0; k < 7; ++k) {
      int i = t + k * 256;
      if (i < 1600) {
        float4 v = ld[k];
        int row = i >> 4, col = (i & 15) * 4;
        *(ushort4*)&e_lds[buf][row * 72 + col] =
            make_ushort4(f2bf(v.x), f2bf(v.y), f2bf(v.z), f2bf(v.w));
      }
    }
    __syncthreads();
    if (r + 1 < mcnt) {
      const float4* nxt = (const float4*)(e + (size_t)(b * N_ + m0 + r + 1) * (N_ * ED_));
#pragma unroll
      for (int k = 0; k < 7; ++k) { int i = t + k * 256; if (i < 1600) ld[k] = nxt[i]; }
    }

    const int bm = b * N_ + m0 + r;
    const float A0 = ws[WS_A + bm * 128 + d0];
    const float A1 = ws[WS_A + bm * 128 + d1];

    f32x4 acc[7][2];
#pragma unroll
    for (int mt = 0; mt < 7; ++mt) { acc[mt][0] = (f32x4)0.f; acc[mt][1] = (f32x4)0.f; }
#pragma unroll
    for (int mt = 0; mt < 7; ++mt) {
      int row = mt * 16 + lr;
      bf16x8 af0 = *(const bf16x8*)&e_lds[buf][row * 72 + lg * 8];
      bf16x8 af1 = *(const bf16x8*)&e_lds[buf][row * 72 + 32 + lg * 8];
#pragma unroll
      for (int nt = 0; nt < 2; ++nt) {
        acc[mt][nt] = MFMA16(af0, bfr[nt][0], acc[mt][nt]);
        acc[mt][nt] = MFMA16(af1, bfr[nt][1], acc[mt][nt]);
      }
    }

#pragma unroll
    for (int mt = 0; mt < 7; ++mt)
#pragma unroll
      for (int j = 0; j < 4; ++j) {
        int node = mt * 16 + lg * 4 + j;
        if (node < N_) {
          float x0 = acc[mt][0][j] + A0 + bvr[mt][j][0];
          float x1 = acc[mt][1][j] + A1 + bvr[mt][j][1];
          s0 += x0; ss0 += x0 * x0;
          s1 += x1; ss1 += x1 * x1;
        }
      }
    buf ^= 1;
  }

  s0 += __shfl_xor(s0, 16);  s0 += __shfl_xor(s0, 32);
  ss0 += __shfl_xor(ss0, 16); ss0 += __shfl_xor(ss0, 32);
  s1 += __shfl_xor(s1, 16);  s1 += __shfl_xor(s1, 32);
  ss1 += __shfl_xor(ss1, 16); ss1 += __shfl_xor(ss1, 32);
  if (l < 16) {
    atomicAdd(&ws[WS_STATS + b * 256 + d0], s0);
    atomicAdd(&ws[WS_STATS + b * 256 + 128 + d0], ss0);
    atomicAdd(&ws[WS_STATS + b * 256 + d1], s1);
    atomicAdd(&ws[WS_STATS + b * 256 + 128 + d1], ss1);
  }
}

// ---------------------------------------------------------------------------
// K0: finalize edge BN -> scale/shift (one block, 128 threads)
// ---------------------------------------------------------------------------
__global__ __launch_bounds__(128) void k0_finalize(
    const float* __restrict__ gamma_e, const float* __restrict__ beta_e,
    float* __restrict__ ws) {
  const int t = threadIdx.x;
  float S = 0.f, SS = 0.f;
#pragma unroll
  for (int j = 0; j < 32; ++j) {
    S  += ws[WS_STATS + j * 256 + t];
    SS += ws[WS_STATS + j * 256 + 128 + t];
  }
  float mean = S * (1.0f / EDGE_SAMPLES);
  float var  = SS * (1.0f / EDGE_SAMPLES) - mean * mean;
  float sc   = gamma_e[t] * rsqrtf(var + EPS_);
  ws[WS_SCSH + t]       = sc;
  ws[WS_SCSH + 128 + t] = beta_e[t] - mean * sc;
}

// ---------------------------------------------------------------------------
// K4: main fused pass. grid 3200, block 512 (8 waves; wave w owns d-cols
// [16w,16w+16)). Direct-global WC fragments; packed bf16 Bv/hnb preloads
// issued before the staging barrier; e staged in LDS.
// ---------------------------------------------------------------------------
__global__ __launch_bounds__(512) void k4_main(
    const float* __restrict__ e, const float* __restrict__ adj,
    const float* __restrict__ WC,
    float* __restrict__ ws, float* __restrict__ out_enorm) {
  __shared__ unsigned short e_lds[112 * 72];   // 15.75 KB
  __shared__ float adj_lds[112];
  const int t  = threadIdx.x;
  const int bm = blockIdx.x;
  const int b  = bm / N_;
  const int w  = t >> 6;
  const int l  = t & 63;
  const int lr = l & 15;
  const int lg = l >> 4;
  const int d0 = w * 16 + lr;

  // (1) issue e loads
  float4 ld[4];
  const float4* ef4 = (const float4*)(e + (size_t)bm * (N_ * ED_));
#pragma unroll
  for (int k = 0; k < 4; ++k) { int i = t + k * 512; if (i < 1600) ld[k] = ef4[i]; }

  // (2) issue independent preloads: packed Bv/hnb, A, scale/shift, WC frags
  unsigned int pk[7][4];
  const unsigned int* pkp = (const unsigned int*)(ws + WS_PK) + b * (N_ * 128);
#pragma unroll
  for (int mt = 0; mt < 7; ++mt)
#pragma unroll
    for (int j = 0; j < 4; ++j) {
      int node = mt * 16 + lg * 4 + j;
      pk[mt][j] = (node < N_) ? pkp[node * 128 + d0] : 0u;
    }
  const float A0  = ws[WS_A + bm * 128 + d0];
  const float sc0 = ws[WS_SCSH + d0];
  const float sh0 = ws[WS_SCSH + 128 + d0];

  bf16x8 bfr[2];
#pragma unroll
  for (int kb = 0; kb < 2; ++kb) {
    const float* wrow = WC + d0 * 64 + kb * 32 + lg * 8;
    float4 u0 = *(const float4*)wrow;
    float4 u1 = *(const float4*)(wrow + 4);
    bf16x8 f;
    f[0] = (short)f2bf(u0.x); f[1] = (short)f2bf(u0.y);
    f[2] = (short)f2bf(u0.z); f[3] = (short)f2bf(u0.w);
    f[4] = (short)f2bf(u1.x); f[5] = (short)f2bf(u1.y);
    f[6] = (short)f2bf(u1.z); f[7] = (short)f2bf(u1.w);
    bfr[kb] = f;
  }

  if (t < N_) adj_lds[t] = adj[bm * N_ + t];

  // (3) stage e -> LDS (bf16)
#pragma unroll
  for (int k = 0; k < 4; ++k) {
    int i = t + k * 512;
    if (i < 1600) {
      float4 v = ld[k];
      int row = i >> 4, col = (i & 15) * 4;
      *(ushort4*)&e_lds[row * 72 + col] =
          make_ushort4(f2bf(v.x), f2bf(v.y), f2bf(v.z), f2bf(v.w));
    }
  }
  for (int i = t; i < 12 * 72; i += 512) e_lds[100 * 72 + i] = 0;
  __syncthreads();

  // (4) GEMM: 14 MFMAs per wave
  f32x4 acc[7];
#pragma unroll
  for (int mt = 0; mt < 7; ++mt) acc[mt] = (f32x4)0.f;
#pragma unroll
  for (int mt = 0; mt < 7; ++mt) {
    int row = mt * 16 + lr;
    bf16x8 af0 = *(const bf16x8*)&e_lds[row * 72 + lg * 8];
    bf16x8 af1 = *(const bf16x8*)&e_lds[row * 72 + 32 + lg * 8];
    acc[mt] = MFMA16(af0, bfr[0], acc[mt]);
    acc[mt] = MFMA16(af1, bfr[1], acc[mt]);
  }

  // (5) epilogue: BN -> relu -> *adj -> sigmoid -> exp
  float den = 0.f;
#pragma unroll
  for (int mt = 0; mt < 7; ++mt)
#pragma unroll
    for (int j = 0; j < 4; ++j) {
      int node = mt * 16 + lg * 4 + j;
      if (node < N_) {
        float bv = __uint_as_float(pk[mt][j] << 16);
        float x  = (acc[mt][j] + A0 + bv) * sc0 + sh0;
        x = fmaxf(x, 0.f) * adj_lds[node];
        float p = __expf(1.f / (1.f + __expf(-x)));
        acc[mt][j] = p; den += p;
      } else acc[mt][j] = 0.f;
    }
  den += __shfl_xor(den, 16); den += __shfl_xor(den, 32);
  const float rc = 1.f / den;

  // (6) normalize, write e_norm, aggregate m
  float msg = 0.f;
  float* outp = out_enorm + (size_t)bm * (N_ * 128);
#pragma unroll
  for (int mt = 0; mt < 7; ++mt)
#pragma unroll
    for (int j = 0; j < 4; ++j) {
      int node = mt * 16 + lg * 4 + j;
      if (node < N_) {
        float v = acc[mt][j] * rc;
        outp[node * 128 + d0] = v;
        float hn = __uint_as_float(pk[mt][j] & 0xffff0000u);
        msg += v * hn;
      }
    }
  msg += __shfl_xor(msg, 16); msg += __shfl_xor(msg, 32);
  if (l < 16) ws[WS_M + bm * 128 + d0] = msg;
}

// ---------------------------------------------------------------------------
// K5a: node BN statistics over m [3200][128]. grid 32, block 256.
// ---------------------------------------------------------------------------
__global__ __launch_bounds__(256) void k5a_nstats(float* __restrict__ ws) {
  __shared__ float red[256];
  const int t = threadIdx.x;
  const int j = blockIdx.x;
  const int d = t & 127, rh = t >> 7;
  float s = 0.f, sssum = 0.f;
  for (int r = j * 100 + rh; r < (j + 1) * 100; r += 2) {
    float v = ws[WS_M + r * 128 + d];
    s += v;
    sssum += v * v;
  }
  red[t] = s;
  __syncthreads();
  if (t < 128) atomicAdd(&ws[WS_NSTATS + t], red[t] + red[t + 128]);
  __syncthreads();
  red[t] = sssum;
  __syncthreads();
  if (t < 128) atomicAdd(&ws[WS_NSTATS + 128 + t], red[t] + red[t + 128]);
}

// ---------------------------------------------------------------------------
// K5b: h_out = h_in + relu(bn_node(m)). grid 1600, block 256.
// ---------------------------------------------------------------------------
__global__ __launch_bounds__(256) void k5b_hout(
    const float* __restrict__ gamma_n, const float* __restrict__ beta_n,
    const float* __restrict__ ws, float* __restrict__ hout) {
  const int idx = blockIdx.x * 256 + threadIdx.x;
  const int d = idx & 127;
  float S  = ws[WS_NSTATS + d];
  float SS = ws[WS_NSTATS + 128 + d];
  float mean = S * (1.0f / (float)NNODE);
  float var  = SS * (1.0f / (float)NNODE) - mean * mean;
  float sc   = gamma_n[d] * rsqrtf(var + EPS_);
  float sh   = beta_n[d] - mean * sc;
  float mv   = ws[WS_M + idx];
  hout[idx]  = ws[WS_HIN + idx] + fmaxf(mv * sc + sh, 0.f);
}

// ---------------------------------------------------------------------------
extern "C" void kernel_launch(void* const* d_in, const int* in_sizes, int n_in,
                              void* d_out, int out_size, void* d_ws, size_t ws_size,
                              hipStream_t stream) {
  (void)in_sizes; (void)n_in; (void)out_size; (void)ws_size;
  const float* h   = (const float*)d_in[0];
  const float* e   = (const float*)d_in[1];
  const float* adj = (const float*)d_in[2];
  const float* WU  = (const float*)d_in[3];
  const float* WV  = (const float*)d_in[4];
  const float* WA  = (const float*)d_in[5];
  const float* WB  = (const float*)d_in[6];
  const float* WC  = (const float*)d_in[7];
  const float* geg = (const float*)d_in[8];
  const float* geb = (const float*)d_in[9];
  const float* gng = (const float*)d_in[10];
  const float* gnb = (const float*)d_in[11];

  float* out = (float*)d_out;   // h_out [409600] then e_norm [40960000]
  float* ws  = (float*)d_ws;

  // zero the atomic accumulators (STATS + SCSH + NSTATS region)
  hipMemsetAsync(ws + WS_STATS, 0, (8192 + 512) * sizeof(float), stream);

  k1_proj    <<<dim3(25, 4),  256, 0, stream>>>(h, WA, WB, WU, WV, ws);
  k2_stats   <<<dim3(32, 15), 256, 0, stream>>>(e, WC, ws);
  k0_finalize<<<1,            128, 0, stream>>>(geg, geb, ws);
  k4_main    <<<3200,         512, 0, stream>>>(e, adj, WC, ws, out + 409600);
  k5a_nstats <<<32,           256, 0, stream>>>(ws);
  k5b_hout   <<<1600,         256, 0, stream>>>(gng, gnb, ws, out);
}